// Round 8
// baseline (242.266 us; speedup 1.0000x reference)
//
#include <hip/hip_runtime.h>

typedef short bf8_t __attribute__((ext_vector_type(8)));   // 8 x bf16
typedef float f32x4 __attribute__((ext_vector_type(4)));

static constexpr int Bc      = 2;
static constexpr int Nv      = 163842;
static constexpr int CIN     = 64;
static constexpr int COUT    = 64;
static constexpr int KK      = 448;                 // 7*CIN
static constexpr int SEVEN_N = 7 * Nv;              // 1146894
static constexpr int THREADS = 512;                 // 8 waves

// ---- Q=2 m-tiling (bf16 main path) ----
static constexpr int LM2     = 2 * KK;              // 896 useful m per tile
static constexpr int MST2    = LM2 + KK;            // 1344 staged (halo)
static constexpr int STRIDE2 = 1352;                // shorts; 676 dw, 676%32=4
static constexpr int NT2     = (SEVEN_N + LM2 - 1) / LM2;    // 1281
static constexpr int TILE2   = 15 * STRIDE2 + 8 + STRIDE2;   // 21640 shorts = 43280 B

__device__ inline int cbase(int c) {
    // +4dw pad every 8 channels: bank(c)=4c+4(c>>3) -> c vs c+8 differ (kills
    // the q0/q1 write collision that r7's plain stride had: 900*8 % 32 == 0).
    return c * STRIDE2 + 8 * (c >> 3);
}

__device__ inline unsigned pack2_bf16(float a, float b) {
    unsigned ua = __builtin_bit_cast(unsigned, a);
    unsigned ub = __builtin_bit_cast(unsigned, b);
    ua = (ua + 0x7FFFu + ((ua >> 16) & 1u)) >> 16;          // RNE
    ub = (ub + 0x7FFFu + ((ub >> 16) & 1u));
    return (ua & 0xFFFFu) | (ub & 0xFFFF0000u);
}

// ---- pre-pass: x fp32 -> bf16 (identical rounding to staging path) ----
__global__ __launch_bounds__(256) void xconv(const float* __restrict__ x,
                                             short* __restrict__ xb, int n) {
    const int i = (blockIdx.x * 256 + threadIdx.x) * 8;
    if (i >= n) return;
    const float4 a = *(const float4*)(x + i);
    const float4 c = *(const float4*)(x + i + 4);
    uint4 o;
    o.x = pack2_bf16(a.x, a.y); o.y = pack2_bf16(a.z, a.w);
    o.z = pack2_bf16(c.x, c.y); o.w = pack2_bf16(c.z, c.w);
    *(uint4*)(xb + i) = o;
}

// ---- main (bf16 x): slot = (mt%4, b) -> all 4 cg of one (mt,b) share an XCD.
// Q=2: 43.3KB LDS -> 3 blk/CU, 24 waves/CU. 8 compute tasks = 1 per wave. ----
__global__ __launch_bounds__(THREADS, 6) void conv_main_bf16(
    const short* __restrict__ xbf,     // (B, Nv, 64) bf16
    const short* __restrict__ Wb,      // bf16 W, row-major [COUT][KK]
    const float* __restrict__ bias,
    const int*   __restrict__ idx,
    float*       __restrict__ out)
{
    __shared__ short tile[TILE2];                            // 43280 B

    const int bid   = blockIdx.x;
    const int s     = bid & 7;         // XCD slot
    const int b     = s & 1;
    const int mtres = s >> 1;          // mt residue mod 4
    const int rr    = bid >> 3;
    const int mt    = (rr >> 2) * 4 + mtres;
    const int cg    = rr & 3;
    if (mt >= NT2) return;

    const int t    = threadIdx.x;
    const int M0   = mt * LM2;
    const int mEnd = min(M0 + MST2, SEVEN_N);
    const short* xb = xbf + (size_t)b * Nv * CIN;

    // ---- gather: 2 threads per m (q = channel octet); 6 passes of 256 m ----
    const int q     = t & 1;
    const int mloc  = t >> 1;          // 0..255
    const int choff = cg * 16 + q * 8; // short offset in 64-ch row

    int iv[6];
    #pragma unroll
    for (int p = 0; p < 6; ++p) {
        const int dm = p * 256 + mloc;
        const int m  = M0 + dm;
        iv[p] = (dm < MST2 && m < mEnd) ? idx[m] : 0;
    }
    bf8_t v[6];
    #pragma unroll
    for (int p = 0; p < 6; ++p)
        v[p] = *(const bf8_t*)(xb + (size_t)iv[p] * CIN + choff);
    #pragma unroll
    for (int p = 0; p < 6; ++p) {
        const int dm = p * 256 + mloc;
        const int m  = M0 + dm;
        if (dm < MST2 && m < mEnd) {
            #pragma unroll
            for (int j = 0; j < 8; ++j) {
                const int c     = q * 8 + j;
                const int shift = (6 * c) & 7;               // == Ta&7 for row c
                tile[cbase(c) + dm + shift] = v[p][j];
            }
        }
    }
    __syncthreads();

    // ---- compute: 8 tasks, exactly one per wave: oc = w&3, r = w>>2 ----
    const int lane = t & 63;
    const int w    = t >> 6;
    const int col  = lane & 15;
    const int hi   = lane >> 4;
    const int oc   = w & 3;
    const int r    = w >> 2;           // 0..1

    const short* wbase = Wb + (oc * 16 + col) * KK + 8 * hi;
    bf8_t bfrag[14];
    #pragma unroll
    for (int k0 = 0; k0 < 14; ++k0)
        bfrag[k0] = *(const bf8_t*)(wbase + 32 * k0);

    const int Ca  = cg * 16 + col;
    const int Ta  = Ca * SEVEN_N + M0;
    const int d0a = (448 - (Ta % 448)) % 448;
    const int sha = Ta & 7;
    const short* abase = &tile[cbase(col) + d0a + sha + 8 * hi + 448 * r];

    f32x4 acc = (f32x4){0.f, 0.f, 0.f, 0.f};
    #pragma unroll
    for (int k0 = 0; k0 < 14; ++k0) {
        const bf8_t afrag = *(const bf8_t*)(abase + 32 * k0);
        acc = __builtin_amdgcn_mfma_f32_16x16x32_bf16(afrag, bfrag[k0], acc, 0, 0, 0);
    }

    const float bo = bias[oc * 16 + col];
    #pragma unroll
    for (int i = 0; i < 4; ++i) {
        const int c_s = 4 * hi + i;
        const int Cs  = cg * 16 + c_s;
        const int Ts  = Cs * SEVEN_N + M0;
        const int d0s = (448 - (Ts % 448)) % 448;
        const int sr  = M0 + d0s + 448 * r;
        if (sr + 448 <= SEVEN_N) {                 // skip straddling rows
            const int n = (Ts + d0s) / 448 + r;
            out[((size_t)b * Nv + n) * COUT + oc * 16 + col] = acc[i] + bo;
        }
    }
}

// ---- fallback (r4 structure, fp32 x) if ws too small for the bf16 copy ----
static constexpr int Q3      = 3;
static constexpr int LM3     = Q3 * KK;             // 1344
static constexpr int MST3    = LM3 + KK;            // 1792
static constexpr int STRIDE3 = 1800;
static constexpr int NT3     = (SEVEN_N + LM3 - 1) / LM3;    // 854
static constexpr int PAIRS   = MST3 / 2;            // 896
static constexpr int PPP     = THREADS / 4;         // 128
static constexpr int PASSES  = PAIRS / PPP;         // 7

__global__ __launch_bounds__(THREADS, 4) void conv_main_f32(
    const float* __restrict__ x,
    const short* __restrict__ Wb,
    const float* __restrict__ bias,
    const int*   __restrict__ idx,
    float*       __restrict__ out)
{
    __shared__ short tile[16 * STRIDE3];

    const int bid  = blockIdx.x;
    const int slot = bid & 7;
    const int cg   = slot >> 1;
    const int b    = slot & 1;
    const int mt   = bid >> 3;
    const int t    = threadIdx.x;
    const int M0   = mt * LM3;
    const int mEnd = min(M0 + MST3, SEVEN_N);
    const float* xb = x + (size_t)b * Nv * CIN;

    const int q    = t & 3;
    const int pidl = t >> 2;
    const int xoff = cg * 16 + q * 4;

    int iv0[PASSES], iv1[PASSES];
    #pragma unroll
    for (int p = 0; p < PASSES; ++p) {
        const int m0 = M0 + 2 * (p * PPP + pidl);
        const bool ok = (m0 < mEnd);
        iv0[p] = ok ? idx[m0] : 0;
        iv1[p] = (ok && m0 + 1 < mEnd) ? idx[m0 + 1] : 0;
    }
    float4 v0[PASSES], v1[PASSES];
    #pragma unroll
    for (int p = 0; p < PASSES; ++p) {
        v0[p] = *(const float4*)(xb + (size_t)iv0[p] * CIN + xoff);
        v1[p] = *(const float4*)(xb + (size_t)iv1[p] * CIN + xoff);
    }
    #pragma unroll
    for (int p = 0; p < PASSES; ++p) {
        const int m0 = M0 + 2 * (p * PPP + pidl);
        if (m0 < mEnd) {
            const float a0[4] = {v0[p].x, v0[p].y, v0[p].z, v0[p].w};
            const float a1[4] = {v1[p].x, v1[p].y, v1[p].z, v1[p].w};
            #pragma unroll
            for (int i = 0; i < 4; ++i) {
                const int c     = q * 4 + i;
                const int shift = (6 * c) & 7;
                const int ppos  = (m0 - M0) + shift;
                *(unsigned*)&tile[c * STRIDE3 + ppos] = pack2_bf16(a0[i], a1[i]);
            }
        }
    }
    __syncthreads();

    const int lane = t & 63;
    const int w    = t >> 6;
    const int col  = lane & 15;
    const int hi   = lane >> 4;
    const int oc   = w & 3;

    const short* wbase = Wb + (oc * 16 + col) * KK + 8 * hi;
    bf8_t bfrag[14];
    #pragma unroll
    for (int k0 = 0; k0 < 14; ++k0)
        bfrag[k0] = *(const bf8_t*)(wbase + 32 * k0);

    const int Ca  = cg * 16 + col;
    const int Ta  = Ca * SEVEN_N + M0;
    const int d0a = (448 - (Ta % 448)) % 448;
    const int sha = Ta & 7;
    const short* abase0 = &tile[col * STRIDE3 + d0a + sha + 8 * hi];
    const float bo = bias[oc * 16 + col];

    for (int task = w; task < 12; task += 8) {
        const int r = task >> 2;
        const short* abase = abase0 + 448 * r;
        f32x4 acc = (f32x4){0.f, 0.f, 0.f, 0.f};
        #pragma unroll
        for (int k0 = 0; k0 < 14; ++k0) {
            const bf8_t afrag = *(const bf8_t*)(abase + 32 * k0);
            acc = __builtin_amdgcn_mfma_f32_16x16x32_bf16(afrag, bfrag[k0], acc, 0, 0, 0);
        }
        #pragma unroll
        for (int i = 0; i < 4; ++i) {
            const int c_s = 4 * hi + i;
            const int Cs  = cg * 16 + c_s;
            const int Ts  = Cs * SEVEN_N + M0;
            const int d0s = (448 - (Ts % 448)) % 448;
            const int sr  = M0 + d0s + 448 * r;
            if (sr + 448 <= SEVEN_N) {
                const int n = (Ts + d0s) / 448 + r;
                out[((size_t)b * Nv + n) * COUT + oc * 16 + col] = acc[i] + bo;
            }
        }
    }
}

// Channel-straddling rows (<=63 per batch): exact fp32, j-parallel.
__global__ __launch_bounds__(256) void conv_cleanup(
    const float* __restrict__ x,
    const float* __restrict__ W,
    const float* __restrict__ bias,
    const int*   __restrict__ idx,
    float*       __restrict__ out)
{
    __shared__ float part[4][64];
    const int C = blockIdx.x;
    const int b = blockIdx.y;
    const int t = threadIdx.x;
    const int o = t & 63;
    const int p = t >> 6;
    const int n = (int)(((long long)(C + 1) * SEVEN_N + 447) / 448) - 1;
    const int s = 448 * n - C * SEVEN_N;
    if (s + 448 <= SEVEN_N) return;
    const float* xb = x + (size_t)b * Nv * CIN;
    float acc = 0.f;
    for (int j = p * 112; j < (p + 1) * 112; ++j) {
        int m = s + j, c = C;
        if (m >= SEVEN_N) { m -= SEVEN_N; c += 1; }
        acc += xb[(size_t)idx[m] * CIN + c] * W[o * KK + j];
    }
    part[p][o] = acc;
    __syncthreads();
    if (p == 0)
        out[((size_t)b * Nv + n) * COUT + o] =
            part[0][o] + part[1][o] + part[2][o] + part[3][o] + bias[o];
}

__global__ void wconv(const float* __restrict__ W, short* __restrict__ Wb) {
    const int i = blockIdx.x * 256 + threadIdx.x;
    if (i < COUT * KK) {
        unsigned u = __builtin_bit_cast(unsigned, W[i]);
        u = (u + 0x7FFFu + ((u >> 16) & 1u)) >> 16;
        Wb[i] = (short)u;
    }
}

extern "C" void kernel_launch(void* const* d_in, const int* in_sizes, int n_in,
                              void* d_out, int out_size, void* d_ws, size_t ws_size,
                              hipStream_t stream) {
    const float* x    = (const float*)d_in[0];
    const float* W    = (const float*)d_in[1];
    const float* bias = (const float*)d_in[2];
    const int*   idx  = (const int*)d_in[3];
    float*       out  = (float*)d_out;
    short*       Wb   = (short*)d_ws;                        // [0, 57344)

    hipLaunchKernelGGL(wconv, dim3((COUT * KK + 255) / 256), dim3(256), 0, stream, W, Wb);

    const int    nxe  = Bc * Nv * CIN;                       // 20,971,776
    const size_t need = 65536 + (size_t)nxe * sizeof(short);
    if (ws_size >= need) {
        short* xbf = (short*)((char*)d_ws + 65536);
        hipLaunchKernelGGL(xconv, dim3((nxe / 8 + 255) / 256), dim3(256), 0, stream,
                           x, xbf, nxe);
        // rounds = ceil(NT2/4) = 321; blocks = 321*4 rr-values * 8 slots
        hipLaunchKernelGGL(conv_main_bf16, dim3(321 * 4 * 8), dim3(THREADS), 0, stream,
                           xbf, Wb, bias, idx, out);
    } else {
        hipLaunchKernelGGL(conv_main_f32, dim3(NT3 * 8), dim3(THREADS), 0, stream,
                           x, Wb, bias, idx, out);
    }
    hipLaunchKernelGGL(conv_cleanup, dim3(CIN, Bc), dim3(256), 0, stream,
                       x, W, bias, idx, out);
}

// Round 9
// 186.868 us; speedup vs baseline: 1.2965x; 1.2965x over previous
//
#include <hip/hip_runtime.h>

typedef short bf8_t __attribute__((ext_vector_type(8)));   // 8 x bf16
typedef float f32x4 __attribute__((ext_vector_type(4)));

static constexpr int Bc      = 2;
static constexpr int Nv      = 163842;
static constexpr int CIN     = 64;
static constexpr int COUT    = 64;
static constexpr int KK      = 448;                 // 7*CIN
static constexpr int SEVEN_N = 7 * Nv;              // 1146894
static constexpr int THREADS = 512;                 // 8 waves

// ---- Q=3 m-tiling (bf16 main path, r7 geometry) ----
static constexpr int LM      = 3 * KK;              // 1344 useful m per tile
static constexpr int MST     = LM + KK;             // 1792 staged (halo)
static constexpr int STRIDE  = 1800;                // shorts per channel row
static constexpr int NT      = (SEVEN_N + LM - 1) / LM;      // 854
static constexpr int NPAIR   = MST / 2;             // 896 m-pairs per tile
static constexpr int TILE_SH = 16 * STRIDE + 32;    // 28832 shorts = 57664 B

__device__ inline int cbase(int c) {
    // +32-short pad after channel 7: q0 (c<8) and q1 (c>=8) write windows land
    // 16 banks apart -> with each q-group spanning all 32 banks via consecutive
    // dwords, total is exactly 2 lanes/bank (free). 32%8==0 keeps 16B alignment.
    return c * STRIDE + 32 * (c >> 3);
}

__device__ inline unsigned pack2_bf16(float a, float b) {
    unsigned ua = __builtin_bit_cast(unsigned, a);
    unsigned ub = __builtin_bit_cast(unsigned, b);
    ua = (ua + 0x7FFFu + ((ua >> 16) & 1u)) >> 16;          // RNE
    ub = (ub + 0x7FFFu + ((ub >> 16) & 1u));
    return (ua & 0xFFFFu) | (ub & 0xFFFF0000u);
}

// ---- pre-pass: x fp32 -> bf16 (identical rounding to staging path) ----
__global__ __launch_bounds__(256) void xconv(const float* __restrict__ x,
                                             short* __restrict__ xb, int n) {
    const int i = (blockIdx.x * 256 + threadIdx.x) * 8;
    if (i >= n) return;
    const float4 a = *(const float4*)(x + i);
    const float4 c = *(const float4*)(x + i + 4);
    uint4 o;
    o.x = pack2_bf16(a.x, a.y); o.y = pack2_bf16(a.z, a.w);
    o.z = pack2_bf16(c.x, c.y); o.w = pack2_bf16(c.z, c.w);
    *(uint4*)(xb + i) = o;
}

// ---- main (bf16 x): slot = (mt%4, b) -> all 4 cg of one (mt,b) share an XCD,
// merging their reads of the same 128B vertex rows in that XCD's L2. ----
__global__ __launch_bounds__(THREADS, 4) void conv_main_bf16(
    const short* __restrict__ xbf,     // (B, Nv, 64) bf16
    const short* __restrict__ Wb,      // bf16 W, row-major [COUT][KK]
    const float* __restrict__ bias,
    const int*   __restrict__ idx,
    float*       __restrict__ out)
{
    __shared__ short tile[TILE_SH];                          // 57664 B -> 2 blk/CU

    const int bid   = blockIdx.x;
    const int s     = bid & 7;         // XCD slot
    const int b     = s & 1;
    const int mtres = s >> 1;          // mt residue mod 4
    const int rr    = bid >> 3;
    const int mt    = (rr >> 2) * 4 + mtres;
    const int cg    = rr & 3;
    if (mt >= NT) return;

    const int t    = threadIdx.x;
    const int M0   = mt * LM;
    const int mEnd = min(M0 + MST, SEVEN_N);
    const short* xb = xbf + (size_t)b * Nv * CIN;

    // ---- gather: 2 threads per m-PAIR (q = channel octet), packed b32 writes ----
    const int q     = t & 1;
    const int pidl  = t >> 1;          // 0..255 pair slot
    const int choff = cg * 16 + q * 8;

    int2 ivp[4];
    #pragma unroll
    for (int p = 0; p < 4; ++p) {
        const int pp = p * 256 + pidl;
        const int m0 = M0 + 2 * pp;
        if (pp < NPAIR && m0 + 1 < SEVEN_N) {
            ivp[p] = *(const int2*)(idx + m0);               // consecutive pair
        } else if (pp < NPAIR && m0 < SEVEN_N) {
            ivp[p].x = idx[m0]; ivp[p].y = idx[m0];
        } else {
            ivp[p].x = 0; ivp[p].y = 0;
        }
    }
    bf8_t v0[4], v1[4];
    #pragma unroll
    for (int p = 0; p < 4; ++p) {
        v0[p] = *(const bf8_t*)(xb + (size_t)ivp[p].x * CIN + choff);
        v1[p] = *(const bf8_t*)(xb + (size_t)ivp[p].y * CIN + choff);
    }

    // ---- W fragments loaded HERE: overlaps W (L2-resident) latency with the
    // in-flight x gather; consumed only after the barrier. ----
    const int lane = t & 63;
    const int w    = t >> 6;
    const int col  = lane & 15;
    const int hi   = lane >> 4;
    const int oc   = w & 3;
    const short* wbase = Wb + (oc * 16 + col) * KK + 8 * hi;
    bf8_t bfrag[14];
    #pragma unroll
    for (int k0 = 0; k0 < 14; ++k0)
        bfrag[k0] = *(const bf8_t*)(wbase + 32 * k0);

    // ---- LDS staging: 8 packed b32 writes per pass (vs r7's 16 b16) ----
    #pragma unroll
    for (int p = 0; p < 4; ++p) {
        const int pp = p * 256 + pidl;
        const int m0 = M0 + 2 * pp;
        if (pp < NPAIR && m0 < mEnd) {
            const int dm = 2 * pp;
            #pragma unroll
            for (int j = 0; j < 8; ++j) {
                const int c     = q * 8 + j;
                const int shift = (6 * c) & 7;               // == Ta&7, even
                const unsigned lo = (unsigned short)v0[p][j];
                const unsigned hi2 = (unsigned short)v1[p][j];
                *(unsigned*)&tile[cbase(c) + dm + shift] = lo | (hi2 << 16);
            }
        }
    }
    __syncthreads();

    // ---- compute: 12 tasks (oc = task&3, r = task>>2) over 8 waves ----
    const int Ca  = cg * 16 + col;
    const int Ta  = Ca * SEVEN_N + M0;
    const int d0a = (448 - (Ta % 448)) % 448;
    const int sha = Ta & 7;
    const short* abase0 = &tile[cbase(col) + d0a + sha + 8 * hi];
    const float bo = bias[oc * 16 + col];

    for (int task = w; task < 12; task += 8) {
        const int r = task >> 2;
        const short* abase = abase0 + 448 * r;

        f32x4 acc = (f32x4){0.f, 0.f, 0.f, 0.f};
        #pragma unroll
        for (int k0 = 0; k0 < 14; ++k0) {
            const bf8_t afrag = *(const bf8_t*)(abase + 32 * k0);
            acc = __builtin_amdgcn_mfma_f32_16x16x32_bf16(afrag, bfrag[k0], acc, 0, 0, 0);
        }
        #pragma unroll
        for (int i = 0; i < 4; ++i) {
            const int c_s = 4 * hi + i;
            const int Cs  = cg * 16 + c_s;
            const int Ts  = Cs * SEVEN_N + M0;
            const int d0s = (448 - (Ts % 448)) % 448;
            const int sr  = M0 + d0s + 448 * r;
            if (sr + 448 <= SEVEN_N) {               // skip straddling rows
                const int n = (Ts + d0s) / 448 + r;
                out[((size_t)b * Nv + n) * COUT + oc * 16 + col] = acc[i] + bo;
            }
        }
    }
}

// ---- fallback (r4 structure, fp32 x) if ws too small for the bf16 copy ----
static constexpr int PAIRS   = MST / 2;             // 896
static constexpr int PPP     = THREADS / 4;         // 128
static constexpr int PASSES  = PAIRS / PPP;         // 7

__global__ __launch_bounds__(THREADS, 4) void conv_main_f32(
    const float* __restrict__ x,
    const short* __restrict__ Wb,
    const float* __restrict__ bias,
    const int*   __restrict__ idx,
    float*       __restrict__ out)
{
    __shared__ short tile[16 * STRIDE];

    const int bid  = blockIdx.x;
    const int slot = bid & 7;
    const int cg   = slot >> 1;
    const int b    = slot & 1;
    const int mt   = bid >> 3;
    const int t    = threadIdx.x;
    const int M0   = mt * LM;
    const int mEnd = min(M0 + MST, SEVEN_N);
    const float* xb = x + (size_t)b * Nv * CIN;

    const int q    = t & 3;
    const int pidl = t >> 2;
    const int xoff = cg * 16 + q * 4;

    int iv0[PASSES], iv1[PASSES];
    #pragma unroll
    for (int p = 0; p < PASSES; ++p) {
        const int m0 = M0 + 2 * (p * PPP + pidl);
        const bool ok = (m0 < mEnd);
        iv0[p] = ok ? idx[m0] : 0;
        iv1[p] = (ok && m0 + 1 < mEnd) ? idx[m0 + 1] : 0;
    }
    float4 v0[PASSES], v1[PASSES];
    #pragma unroll
    for (int p = 0; p < PASSES; ++p) {
        v0[p] = *(const float4*)(xb + (size_t)iv0[p] * CIN + xoff);
        v1[p] = *(const float4*)(xb + (size_t)iv1[p] * CIN + xoff);
    }
    #pragma unroll
    for (int p = 0; p < PASSES; ++p) {
        const int m0 = M0 + 2 * (p * PPP + pidl);
        if (m0 < mEnd) {
            const float a0[4] = {v0[p].x, v0[p].y, v0[p].z, v0[p].w};
            const float a1[4] = {v1[p].x, v1[p].y, v1[p].z, v1[p].w};
            #pragma unroll
            for (int i = 0; i < 4; ++i) {
                const int c     = q * 4 + i;
                const int shift = (6 * c) & 7;
                const int ppos  = (m0 - M0) + shift;
                *(unsigned*)&tile[c * STRIDE + ppos] = pack2_bf16(a0[i], a1[i]);
            }
        }
    }
    __syncthreads();

    const int lane = t & 63;
    const int w    = t >> 6;
    const int col  = lane & 15;
    const int hi   = lane >> 4;
    const int oc   = w & 3;

    const short* wbase = Wb + (oc * 16 + col) * KK + 8 * hi;
    bf8_t bfrag[14];
    #pragma unroll
    for (int k0 = 0; k0 < 14; ++k0)
        bfrag[k0] = *(const bf8_t*)(wbase + 32 * k0);

    const int Ca  = cg * 16 + col;
    const int Ta  = Ca * SEVEN_N + M0;
    const int d0a = (448 - (Ta % 448)) % 448;
    const int sha = Ta & 7;
    const short* abase0 = &tile[col * STRIDE + d0a + sha + 8 * hi];
    const float bo = bias[oc * 16 + col];

    for (int task = w; task < 12; task += 8) {
        const int r = task >> 2;
        const short* abase = abase0 + 448 * r;
        f32x4 acc = (f32x4){0.f, 0.f, 0.f, 0.f};
        #pragma unroll
        for (int k0 = 0; k0 < 14; ++k0) {
            const bf8_t afrag = *(const bf8_t*)(abase + 32 * k0);
            acc = __builtin_amdgcn_mfma_f32_16x16x32_bf16(afrag, bfrag[k0], acc, 0, 0, 0);
        }
        #pragma unroll
        for (int i = 0; i < 4; ++i) {
            const int c_s = 4 * hi + i;
            const int Cs  = cg * 16 + c_s;
            const int Ts  = Cs * SEVEN_N + M0;
            const int d0s = (448 - (Ts % 448)) % 448;
            const int sr  = M0 + d0s + 448 * r;
            if (sr + 448 <= SEVEN_N) {
                const int n = (Ts + d0s) / 448 + r;
                out[((size_t)b * Nv + n) * COUT + oc * 16 + col] = acc[i] + bo;
            }
        }
    }
}

// Channel-straddling rows (<=63 per batch): exact fp32, j-parallel.
__global__ __launch_bounds__(256) void conv_cleanup(
    const float* __restrict__ x,
    const float* __restrict__ W,
    const float* __restrict__ bias,
    const int*   __restrict__ idx,
    float*       __restrict__ out)
{
    __shared__ float part[4][64];
    const int C = blockIdx.x;
    const int b = blockIdx.y;
    const int t = threadIdx.x;
    const int o = t & 63;
    const int p = t >> 6;
    const int n = (int)(((long long)(C + 1) * SEVEN_N + 447) / 448) - 1;
    const int s = 448 * n - C * SEVEN_N;
    if (s + 448 <= SEVEN_N) return;
    const float* xb = x + (size_t)b * Nv * CIN;
    float acc = 0.f;
    for (int j = p * 112; j < (p + 1) * 112; ++j) {
        int m = s + j, c = C;
        if (m >= SEVEN_N) { m -= SEVEN_N; c += 1; }
        acc += xb[(size_t)idx[m] * CIN + c] * W[o * KK + j];
    }
    part[p][o] = acc;
    __syncthreads();
    if (p == 0)
        out[((size_t)b * Nv + n) * COUT + o] =
            part[0][o] + part[1][o] + part[2][o] + part[3][o] + bias[o];
}

__global__ void wconv(const float* __restrict__ W, short* __restrict__ Wb) {
    const int i = blockIdx.x * 256 + threadIdx.x;
    if (i < COUT * KK) {
        unsigned u = __builtin_bit_cast(unsigned, W[i]);
        u = (u + 0x7FFFu + ((u >> 16) & 1u)) >> 16;
        Wb[i] = (short)u;
    }
}

extern "C" void kernel_launch(void* const* d_in, const int* in_sizes, int n_in,
                              void* d_out, int out_size, void* d_ws, size_t ws_size,
                              hipStream_t stream) {
    const float* x    = (const float*)d_in[0];
    const float* W    = (const float*)d_in[1];
    const float* bias = (const float*)d_in[2];
    const int*   idx  = (const int*)d_in[3];
    float*       out  = (float*)d_out;
    short*       Wb   = (short*)d_ws;                        // [0, 57344)

    hipLaunchKernelGGL(wconv, dim3((COUT * KK + 255) / 256), dim3(256), 0, stream, W, Wb);

    const int    nxe  = Bc * Nv * CIN;                       // 20,971,776
    const size_t need = 65536 + (size_t)nxe * sizeof(short);
    if (ws_size >= need) {
        short* xbf = (short*)((char*)d_ws + 65536);
        hipLaunchKernelGGL(xconv, dim3((nxe / 8 + 255) / 256), dim3(256), 0, stream,
                           x, xbf, nxe);
        // rounds = ceil(NT/4) = 214 -> rr = 214*4 values x 8 slots
        hipLaunchKernelGGL(conv_main_bf16, dim3(214 * 4 * 8), dim3(THREADS), 0, stream,
                           xbf, Wb, bias, idx, out);
    } else {
        hipLaunchKernelGGL(conv_main_f32, dim3(NT * 8), dim3(THREADS), 0, stream,
                           x, Wb, bias, idx, out);
    }
    hipLaunchKernelGGL(conv_cleanup, dim3(CIN, Bc), dim3(256), 0, stream,
                       x, W, bias, idx, out);
}